// Round 7
// baseline (388.734 us; speedup 1.0000x reference)
//
#include <hip/hip_runtime.h>

#define NN 100000
#define NE 1600000
#define CH 4096                                  // edges per chunk
#define NCHUNK ((NE + CH - 1) / CH)              // 391
#define NBUCK ((NN + 255) / 256)                 // 391 (256-node buckets = fused blocks)

__device__ __forceinline__ float wave_red(float v) {
#pragma unroll
    for (int off = 32; off > 0; off >>= 1) v += __shfl_down(v, off, 64);
    return v;
}

// ---------------- build phase: bucket sort, zero global atomics --------------
__global__ __launch_bounds__(256) void hist_kernel(
    const int* __restrict__ ei, int* __restrict__ hist)
{
    __shared__ int h[NBUCK];
    int t = threadIdx.x, c = blockIdx.x;
    for (int b = t; b < NBUCK; b += 256) h[b] = 0;
    __syncthreads();
    int base = c * CH;
    for (int i = t; i < CH; i += 256) {
        int e = base + i;
        if (e < NE) atomicAdd(&h[ei[e] >> 8], 1);
    }
    __syncthreads();
    for (int b = t; b < NBUCK; b += 256) hist[c * NBUCK + b] = h[b];
}

__global__ __launch_bounds__(512) void bscan_kernel(
    const int* __restrict__ hist, int* __restrict__ baseT, int* __restrict__ colTotal)
{
    __shared__ int buf[2][512];
    int b = blockIdx.x, t = threadIdx.x;
    int v = (t < NCHUNK) ? hist[t * NBUCK + b] : 0;
    buf[0][t] = v;
    __syncthreads();
    int src = 0;
    for (int d = 1; d < 512; d <<= 1) {
        int nv = buf[src][t] + ((t >= d) ? buf[src][t - d] : 0);
        buf[src ^ 1][t] = nv;
        src ^= 1;
        __syncthreads();
    }
    if (t < NCHUNK) baseT[b * NCHUNK + t] = buf[src][t] - v;   // exclusive over chunks
    if (t == NCHUNK - 1) colTotal[b] = buf[src][t];
}

__global__ __launch_bounds__(512) void boff_kernel(
    const int* __restrict__ colTotal, int* __restrict__ b_off)
{
    __shared__ int buf[2][512];
    int t = threadIdx.x;
    int v = (t < NBUCK) ? colTotal[t] : 0;
    buf[0][t] = v;
    __syncthreads();
    int src = 0;
    for (int d = 1; d < 512; d <<= 1) {
        int nv = buf[src][t] + ((t >= d) ? buf[src][t - d] : 0);
        buf[src ^ 1][t] = nv;
        src ^= 1;
        __syncthreads();
    }
    if (t < NBUCK) b_off[t] = buf[src][t] - v;
    if (t == NBUCK - 1) b_off[NBUCK] = buf[src][t];            // = NE
}

__global__ __launch_bounds__(256) void fillb_kernel(
    const int* __restrict__ ei, const float* __restrict__ eattr,
    const int* __restrict__ baseT, const int* __restrict__ b_off,
    float4* __restrict__ rec)
{
    __shared__ int sslot[NBUCK];
    int t = threadIdx.x, c = blockIdx.x;
    for (int b = t; b < NBUCK; b += 256)
        sslot[b] = b_off[b] + baseT[b * NCHUNK + c];
    __syncthreads();
    int base = c * CH;
    for (int i = t; i < CH; i += 256) {
        int e = base + i;
        if (e < NE) {
            int row = ei[e];
            int slot = atomicAdd(&sslot[row >> 8], 1);
            float2 ea = reinterpret_cast<const float2*>(eattr)[e];
            float4 v;
            v.x = __int_as_float(row);
            v.y = __int_as_float(ei[NE + e]);
            v.z = ea.x; v.w = ea.y;
            rec[slot] = v;
        }
    }
}

// ============ FUSED layer kernel: weight-amortized 4-edge batch ==============
// r0-r6 exonerated every vector-side resource (waves x4, ILP, payload/2,
// traffic/2 -> all ~no change; all pipes <25%). Remaining suspect: the
// PER-CU SCALAR PIPE. At VGPR=40-56 the ~192 uniform weights of the edge
// MLP cannot be register-resident -> s_load re-fetch per edge, all waves
// queue on the one scalar unit. Fix: weights OUTER, 4 edges INNER -> each
// weight s_load serves 4 edges; gathers forced live-simultaneously (all 4
// feed one FMA chain). 512-thr blocks: VGPR budget 256/wave for ~170 live.
template <bool WRITE_REC, bool NEED_SUM>
__global__ __launch_bounds__(512, 2) void fused_kernel(
    float4* __restrict__ rec, const int* __restrict__ b_off,
    const float* __restrict__ gptr,
    const float* __restrict__ eW1, const float* __restrict__ eB1,
    const float* __restrict__ eW2, const float* __restrict__ eB2,
    const float* __restrict__ xin,
    const float* __restrict__ nW1, const float* __restrict__ nB1,
    const float* __restrict__ nW2, const float* __restrict__ nB2,
    float* __restrict__ xout, float* __restrict__ sums)
{
    __shared__ float sPrT[16 * 256];             // 16 KB, transposed: [q*256+li]
    __shared__ float sagg[256][2];               // 2 KB
    __shared__ float redE[8][2];
    __shared__ float redN[4][8];
    int tid = threadIdx.x;
    ((float*)sagg)[tid] = 0.f;                   // 512 threads cover 512 floats

    int n0 = blockIdx.x * 256;
    bool own = (tid < 256) && (n0 + tid < NN);
    if (own) {
        // row-projection for own node, computed in-block (128 FMAs, once)
        const float4* xi = reinterpret_cast<const float4*>(xin + (size_t)(n0 + tid) * 8);
        float4 a0 = xi[0], a1 = xi[1];
        float xv[8] = {a0.x, a0.y, a0.z, a0.w, a1.x, a1.y, a1.z, a1.w};
        float pr[16];
#pragma unroll
        for (int q = 0; q < 16; q++) pr[q] = 0.f;
#pragma unroll
        for (int k = 0; k < 8; k++) {
            float v = xv[k];
#pragma unroll
            for (int q = 0; q < 16; q++) pr[q] += v * eW1[(1 + k) * 16 + q];
        }
#pragma unroll
        for (int q = 0; q < 16; q++) sPrT[q * 256 + tid] = pr[q];
    }
    __syncthreads();

    int e0 = b_off[blockIdx.x], e1 = b_off[blockIdx.x + 1];

    float gval = gptr[0];
    float gterm[16];
#pragma unroll
    for (int q = 0; q < 16; q++) gterm[q] = eB1[q] + gval * eW1[q];

    float t0 = 0.f, t1 = 0.f;
    for (int base = e0 + tid; base < e1; base += 4 * 512) {
        bool v_[4];
        float4 rb[4];
#pragma unroll
        for (int j = 0; j < 4; j++) {
            int e = base + j * 512;
            v_[j] = (e < e1);
            rb[j] = v_[j] ? rec[e]
                          : make_float4(__int_as_float(n0), __int_as_float(0), 0.f, 0.f);
        }
        float xcv[4][8];
#pragma unroll
        for (int j = 0; j < 4; j++) {
            int col = __float_as_int(rb[j].y);
            const float4* p = reinterpret_cast<const float4*>(xin + (size_t)col * 8);
            float4 a = p[0], b = p[1];
            xcv[j][0] = a.x; xcv[j][1] = a.y; xcv[j][2] = a.z; xcv[j][3] = a.w;
            xcv[j][4] = b.x; xcv[j][5] = b.y; xcv[j][6] = b.z; xcv[j][7] = b.w;
        }
        float h[4][16];
#pragma unroll
        for (int j = 0; j < 4; j++) {
            int li = __float_as_int(rb[j].x) - n0;
#pragma unroll
            for (int q = 0; q < 16; q++) h[j][q] = gterm[q] + sPrT[q * 256 + li];
        }
        // ---- col-projection: weight OUTER, 4 edges INNER (scalar load /4) ----
#pragma unroll
        for (int k = 0; k < 8; k++) {
#pragma unroll
            for (int q = 0; q < 16; q++) {
                float w = eW1[(9 + k) * 16 + q];
                h[0][q] += xcv[0][k] * w;
                h[1][q] += xcv[1][k] * w;
                h[2][q] += xcv[2][k] * w;
                h[3][q] += xcv[3][k] * w;
            }
        }
#pragma unroll
        for (int q = 0; q < 16; q++) {
            float w17 = eW1[17 * 16 + q], w18 = eW1[18 * 16 + q];
#pragma unroll
            for (int j = 0; j < 4; j++)
                h[j][q] += rb[j].z * w17 + rb[j].w * w18;
        }
        float s0[4], s1[4];
#pragma unroll
        for (int j = 0; j < 4; j++) { s0[j] = eB2[0]; s1[j] = eB2[1]; }
#pragma unroll
        for (int q = 0; q < 16; q++) {
            float w0 = eW2[2 * q], w1 = eW2[2 * q + 1];
#pragma unroll
            for (int j = 0; j < 4; j++) {
                float rr = fmaxf(h[j][q], 0.f);
                s0[j] += rr * w0;
                s1[j] += rr * w1;
            }
        }
#pragma unroll
        for (int j = 0; j < 4; j++) if (v_[j]) {
            int e = base + j * 512;
            int li = __float_as_int(rb[j].x) - n0;
            if (WRITE_REC)
                rec[e] = make_float4(rb[j].x, rb[j].y, s0[j], s1[j]);
            atomicAdd(&sagg[li][0], s0[j]);
            atomicAdd(&sagg[li][1], s1[j]);
            t0 += s0[j]; t1 += s1[j];
        }
    }

    if (NEED_SUM) {
        float r0 = wave_red(t0);
        float r1 = wave_red(t1);
        int wave = tid >> 6, lane = tid & 63;
        if (lane == 0) { redE[wave][0] = r0; redE[wave][1] = r1; }
    }
    __syncthreads();   // sagg complete (and redE visible)
    if (NEED_SUM && tid == 0) {
        float s0 = 0.f, s1 = 0.f;
#pragma unroll
        for (int w = 0; w < 8; w++) { s0 += redE[w][0]; s1 += redE[w][1]; }
        atomicAdd(&sums[0], s0);
        atomicAdd(&sums[1], s1);
    }

    // ---------------- phase 2: node MLP (threads 0..255) ----------------
    float out[8];
#pragma unroll
    for (int m = 0; m < 8; m++) out[m] = 0.f;

    if (own) {
        int n = n0 + tid;
        float in[11];
        in[0] = gval;
        const float4* xi = reinterpret_cast<const float4*>(xin + (size_t)n * 8);
        float4 a0 = xi[0], a1 = xi[1];
        in[1] = a0.x; in[2] = a0.y; in[3] = a0.z; in[4] = a0.w;
        in[5] = a1.x; in[6] = a1.y; in[7] = a1.z; in[8] = a1.w;
        in[9] = sagg[tid][0]; in[10] = sagg[tid][1];

        float h[16];
#pragma unroll
        for (int q = 0; q < 16; q++) h[q] = nB1[q];
#pragma unroll
        for (int k = 0; k < 11; k++) {
            float v = in[k];
#pragma unroll
            for (int q = 0; q < 16; q++) h[q] += v * nW1[k * 16 + q];
        }
#pragma unroll
        for (int m = 0; m < 8; m++) out[m] = nB2[m];
#pragma unroll
        for (int q = 0; q < 16; q++) {
            float hq = fmaxf(h[q], 0.f);
#pragma unroll
            for (int m = 0; m < 8; m++) out[m] += hq * nW2[q * 8 + m];
        }
        float4* xo = reinterpret_cast<float4*>(xout + (size_t)n * 8);
        xo[0] = make_float4(out[0], out[1], out[2], out[3]);
        xo[1] = make_float4(out[4], out[5], out[6], out[7]);
    }
    if (NEED_SUM) {
        // owners are waves 0..3 only; reduce within those waves
        float r[8];
#pragma unroll
        for (int m = 0; m < 8; m++) r[m] = wave_red(out[m]);
        int wave = tid >> 6, lane = tid & 63;
        if (wave < 4 && lane == 0) {
#pragma unroll
            for (int m = 0; m < 8; m++) redN[wave][m] = r[m];
        }
        __syncthreads();
        if (tid == 0) {
#pragma unroll
            for (int m = 0; m < 8; m++) {
                float s = redN[0][m] + redN[1][m] + redN[2][m] + redN[3][m];
                atomicAdd(&sums[2 + m], s);
            }
        }
    }
}

// ---------------- global block: MLP(11->16->1), single thread ----------------
__global__ void glob_kernel(const float* __restrict__ sums,
                            const float* __restrict__ gold,
                            const float* __restrict__ W1, const float* __restrict__ B1,
                            const float* __restrict__ W2, const float* __restrict__ B2,
                            float* __restrict__ gnew)
{
    if (threadIdx.x == 0 && blockIdx.x == 0) {
        float in[11];
#pragma unroll
        for (int j = 0; j < 8; j++) in[j] = sums[2 + j] * (1.0f / NN);
        in[8] = sums[0] * (1.0f / NE);
        in[9] = sums[1] * (1.0f / NE);
        in[10] = gold[0];
        float acc = B2[0];
#pragma unroll
        for (int j = 0; j < 16; j++) {
            float h = B1[j];
#pragma unroll
            for (int k = 0; k < 11; k++) h += in[k] * W1[k * 16 + j];
            acc += fmaxf(h, 0.f) * W2[j];
        }
        gnew[0] = acc;
    }
}

extern "C" void kernel_launch(void* const* d_in, const int* in_sizes, int n_in,
                              void* d_out, int out_size, void* d_ws, size_t ws_size,
                              hipStream_t stream) {
    const float* x     = (const float*)d_in[0];
    const int*   ei    = (const int*)d_in[1];
    const float* eattr = (const float*)d_in[2];
    const float* g     = (const float*)d_in[3];
    const float* eW1 = (const float*)d_in[4];
    const float* eB1 = (const float*)d_in[5];
    const float* eW2 = (const float*)d_in[6];
    const float* eB2 = (const float*)d_in[7];
    const float* nW1 = (const float*)d_in[8];
    const float* nB1 = (const float*)d_in[9];
    const float* nW2 = (const float*)d_in[10];
    const float* nB2 = (const float*)d_in[11];
    const float* gW1 = (const float*)d_in[12];
    const float* gB1 = (const float*)d_in[13];
    const float* gW2 = (const float*)d_in[14];
    const float* gB2 = (const float*)d_in[15];
    float* out = (float*)d_out;

    char* ws = (char*)d_ws;
    float*  xb0   = (float*)(ws);                  // 3,200,000
    float*  xb1   = (float*)(ws + 3200000);        // 3,200,000 -> 6,400,000
    int*    b_off = (int*)  (ws + 6400000);        // 392*4 = 1,568 -> pad 1,600
    float*  sums  = (float*)(ws + 6401600);        // 2 slabs x 16 floats = 128 B
    float*  g1    = (float*)(ws + 6401728);
    float*  g2    = g1 + 1;
    float4* rec   = (float4*)(ws + 6401792);       // 25,600,000 -> 32,001,792 total
    // build-phase temporaries alias xb1 (dead until layer-1 phase 2):
    int*    hist     = (int*)xb1;                          // 391*391*4 = 611,524
    int*    baseT    = (int*)((char*)xb1 + 611584);        // 611,524
    int*    colTotal = (int*)((char*)xb1 + 1223168);       // 1,564

    dim3 blk(256);
    dim3 fblk(512);
    dim3 cgrid(NCHUNK);                            // 391 chunks
    dim3 bgrid(NBUCK);                             // 391 buckets

    // ---- bucket-sort build (no global atomics) ----
    hipMemsetAsync(sums, 0, 128, stream);
    hist_kernel<<<cgrid, blk, 0, stream>>>(ei, hist);
    bscan_kernel<<<bgrid, 512, 0, stream>>>(hist, baseT, colTotal);
    boff_kernel<<<1, 512, 0, stream>>>(colTotal, b_off);
    fillb_kernel<<<cgrid, blk, 0, stream>>>(ei, eattr, baseT, b_off, rec);

    // ---- layer 0: x(d_in) -> xb0; rec.zw: ea -> L0 edge emb ----
    fused_kernel<true, true><<<bgrid, fblk, 0, stream>>>(
        rec, b_off, g,
        eW1, eB1, eW2, eB2,
        x, nW1, nB1, nW2, nB2,
        xb0, sums);
    glob_kernel<<<1, 64, 0, stream>>>(sums, g, gW1, gB1, gW2, gB2, g1);

    // ---- layer 1: xb0 -> xb1; rec.zw: L0 -> L1 emb ----
    fused_kernel<true, true><<<bgrid, fblk, 0, stream>>>(
        rec, b_off, g1,
        eW1 + 304, eB1 + 16, eW2 + 32, eB2 + 2,
        xb0, nW1 + 176, nB1 + 16, nW2 + 128, nB2 + 8,
        xb1, sums + 16);
    glob_kernel<<<1, 64, 0, stream>>>(sums + 16, g1, gW1 + 176, gB1 + 16, gW2 + 16, gB2 + 1, g2);

    // ---- layer 2: xb1 -> d_out; no rec rewrite, no sums ----
    fused_kernel<false, false><<<bgrid, fblk, 0, stream>>>(
        rec, b_off, g2,
        eW1 + 608, eB1 + 32, eW2 + 64, eB2 + 4,
        xb1, nW1 + 352, nB1 + 32, nW2 + 256, nB2 + 16,
        out, sums);
}

// Round 8
// 343.303 us; speedup vs baseline: 1.1323x; 1.1323x over previous
//
#include <hip/hip_runtime.h>

#define NN 100000
#define NE 1600000
#define CH 4096                                  // edges per chunk (build)
#define NCHUNK ((NE + CH - 1) / CH)              // 391
#define NBUCK ((NN + 255) / 256)                 // 391 (256-node buckets = fused blocks)
#define ECHUNK 1024                              // edges per LDS-staged chunk

__device__ __forceinline__ float wave_red(float v) {
#pragma unroll
    for (int off = 32; off > 0; off >>= 1) v += __shfl_down(v, off, 64);
    return v;
}

// async global->LDS DMA, 16B per lane; LDS dest must be wave-uniform base +
// lane*16 (guide §5); global src is per-lane.
__device__ __forceinline__ void stage16(void* lds, const void* gsrc) {
    __builtin_amdgcn_global_load_lds(
        (const __attribute__((address_space(1))) unsigned int*)gsrc,
        (__attribute__((address_space(3))) unsigned int*)lds,
        16, 0, 0);
}

// ---------------- build phase: bucket sort, zero global atomics --------------
__global__ __launch_bounds__(256) void hist_kernel(
    const int* __restrict__ ei, int* __restrict__ hist)
{
    __shared__ int h[NBUCK];
    int t = threadIdx.x, c = blockIdx.x;
    for (int b = t; b < NBUCK; b += 256) h[b] = 0;
    __syncthreads();
    int base = c * CH;
    for (int i = t; i < CH; i += 256) {
        int e = base + i;
        if (e < NE) atomicAdd(&h[ei[e] >> 8], 1);
    }
    __syncthreads();
    for (int b = t; b < NBUCK; b += 256) hist[c * NBUCK + b] = h[b];
}

__global__ __launch_bounds__(512) void bscan_kernel(
    const int* __restrict__ hist, int* __restrict__ baseT, int* __restrict__ colTotal)
{
    __shared__ int buf[2][512];
    int b = blockIdx.x, t = threadIdx.x;
    int v = (t < NCHUNK) ? hist[t * NBUCK + b] : 0;
    buf[0][t] = v;
    __syncthreads();
    int src = 0;
    for (int d = 1; d < 512; d <<= 1) {
        int nv = buf[src][t] + ((t >= d) ? buf[src][t - d] : 0);
        buf[src ^ 1][t] = nv;
        src ^= 1;
        __syncthreads();
    }
    if (t < NCHUNK) baseT[b * NCHUNK + t] = buf[src][t] - v;   // exclusive over chunks
    if (t == NCHUNK - 1) colTotal[b] = buf[src][t];
}

__global__ __launch_bounds__(512) void boff_kernel(
    const int* __restrict__ colTotal, int* __restrict__ b_off)
{
    __shared__ int buf[2][512];
    int t = threadIdx.x;
    int v = (t < NBUCK) ? colTotal[t] : 0;
    buf[0][t] = v;
    __syncthreads();
    int src = 0;
    for (int d = 1; d < 512; d <<= 1) {
        int nv = buf[src][t] + ((t >= d) ? buf[src][t - d] : 0);
        buf[src ^ 1][t] = nv;
        src ^= 1;
        __syncthreads();
    }
    if (t < NBUCK) b_off[t] = buf[src][t] - v;
    if (t == NBUCK - 1) b_off[NBUCK] = buf[src][t];            // = NE
}

// record split: immutable 4B key (li<<17 | col) + mutable 8B float2 stream.
__global__ __launch_bounds__(256) void fillb_kernel(
    const int* __restrict__ ei, const float* __restrict__ eattr,
    const int* __restrict__ baseT, const int* __restrict__ b_off,
    int* __restrict__ keys, float2* __restrict__ attrS)
{
    __shared__ int sslot[NBUCK];
    int t = threadIdx.x, c = blockIdx.x;
    for (int b = t; b < NBUCK; b += 256)
        sslot[b] = b_off[b] + baseT[b * NCHUNK + c];
    __syncthreads();
    int base = c * CH;
    for (int i = t; i < CH; i += 256) {
        int e = base + i;
        if (e < NE) {
            int row = ei[e];
            int slot = atomicAdd(&sslot[row >> 8], 1);
            keys[slot] = ((row & 255) << 17) | ei[NE + e];
            attrS[slot] = reinterpret_cast<const float2*>(eattr)[e];
        }
    }
}

// ============ FUSED layer kernel: LDS-staged edge stream (DMA dbuf) ==========
// r0-r7: per-edge cost pinned ~24cyc regardless of waves/ILP/payload/scalar.
// Surviving suspect: rec loads (25.6MB HBM stream, ~900cy) head every edge's
// dependent chain, and vmcnt waits expose it per-iteration. Fix: stream edge
// records into LDS via global_load_lds (fire-and-forget DMA), double-buffered
// 1024-edge chunks -> ONE vmcnt drain (at the chunk barrier) per 1024 edges.
// Per-edge chain collapses to ds_read(key) -> x[col] gather (L2) -> VALU.
template <bool WRITE_EMB, bool NEED_SUM>
__global__ __launch_bounds__(512, 4) void fused_kernel(
    const int* __restrict__ keys,
    const float2* __restrict__ ein, float2* __restrict__ eout,
    const int* __restrict__ b_off,
    const float* __restrict__ gptr,
    const float* __restrict__ eW1, const float* __restrict__ eB1,
    const float* __restrict__ eW2, const float* __restrict__ eB2,
    const float* __restrict__ xin,
    const float* __restrict__ nW1, const float* __restrict__ nB1,
    const float* __restrict__ nW2, const float* __restrict__ nB2,
    float* __restrict__ xout, float* __restrict__ sums)
{
    __shared__ float  sPr[256][20];              // 20KB, pad 20: b128-aligned, banks spread
    __shared__ float  sagg[256][2];              // 2KB
    __shared__ int    kbuf[2][ECHUNK];           // 8KB
    __shared__ float2 abuf[2][ECHUNK];           // 16KB
    __shared__ float  redE[8][2];
    __shared__ float  redN[4][8];
    int tid = threadIdx.x;
    ((float*)sagg)[tid] = 0.f;                   // 512 threads cover 512 floats

    int n0 = blockIdx.x * 256;
    float gval = gptr[0];
    bool own = (tid < 256) && (n0 + tid < NN);
    float xv[8];
    if (own) {
        const float4* xi = reinterpret_cast<const float4*>(xin + (size_t)(n0 + tid) * 8);
        float4 a0 = xi[0], a1 = xi[1];
        xv[0] = a0.x; xv[1] = a0.y; xv[2] = a0.z; xv[3] = a0.w;
        xv[4] = a1.x; xv[5] = a1.y; xv[6] = a1.z; xv[7] = a1.w;
        float pr[16];
#pragma unroll
        for (int q = 0; q < 16; q++) pr[q] = 0.f;
#pragma unroll
        for (int k = 0; k < 8; k++) {
            float v = xv[k];
#pragma unroll
            for (int q = 0; q < 16; q++) pr[q] += v * eW1[(1 + k) * 16 + q];
        }
        float4* pw = reinterpret_cast<float4*>(&sPr[tid][0]);
#pragma unroll
        for (int t4 = 0; t4 < 4; t4++)
            pw[t4] = make_float4(pr[4*t4], pr[4*t4+1], pr[4*t4+2], pr[4*t4+3]);
    }

    int e0 = b_off[blockIdx.x], e1 = b_off[blockIdx.x + 1];
    int a0 = e0 & ~3;                            // 16B-aligned window base
    int nc = (e1 - a0 + ECHUNK - 1) / ECHUNK;

    // stage chunk 0 into buffer 0 (keys: 4KB by waves 0-3; attr: 8KB by all)
    if (tid < 256) stage16(&kbuf[0][tid * 4], keys + a0 + tid * 4);
    stage16(&abuf[0][tid * 2], ein + a0 + tid * 2);

    float gterm[16];
#pragma unroll
    for (int q = 0; q < 16; q++) gterm[q] = eB1[q] + gval * eW1[q];

    float t0 = 0.f, t1 = 0.f;
    for (int c = 0; c < nc; c++) {
        __syncthreads();   // drains DMA of buf[c&1]; buf[(c+1)&1] free (compute c-1 done)
        int cur = c & 1;
        if (c + 1 < nc) {
            int wb = a0 + (c + 1) * ECHUNK;
            if (tid < 256) stage16(&kbuf[cur ^ 1][tid * 4], keys + wb + tid * 4);
            stage16(&abuf[cur ^ 1][tid * 2], ein + wb + tid * 2);
        }
        int cbase = a0 + c * ECHUNK;
#pragma unroll
        for (int j = 0; j < 2; j++) {
            int idx = tid + j * 512;
            int e = cbase + idx;
            if (e < e0 || e >= e1) continue;
            int k = kbuf[cur][idx];
            float2 ea = abuf[cur][idx];
            int li = k >> 17, col = k & 0x1FFFF;
            const float4* xc4 = reinterpret_cast<const float4*>(xin + (size_t)col * 8);
            float4 c0 = xc4[0], c1 = xc4[1];
            const float4* pr4 = reinterpret_cast<const float4*>(&sPr[li][0]);
            float4 p0 = pr4[0], p1 = pr4[1], p2 = pr4[2], p3 = pr4[3];
            float h[16];
            h[0]  = gterm[0]  + p0.x; h[1]  = gterm[1]  + p0.y;
            h[2]  = gterm[2]  + p0.z; h[3]  = gterm[3]  + p0.w;
            h[4]  = gterm[4]  + p1.x; h[5]  = gterm[5]  + p1.y;
            h[6]  = gterm[6]  + p1.z; h[7]  = gterm[7]  + p1.w;
            h[8]  = gterm[8]  + p2.x; h[9]  = gterm[9]  + p2.y;
            h[10] = gterm[10] + p2.z; h[11] = gterm[11] + p2.w;
            h[12] = gterm[12] + p3.x; h[13] = gterm[13] + p3.y;
            h[14] = gterm[14] + p3.z; h[15] = gterm[15] + p3.w;
            float xc[8] = {c0.x, c0.y, c0.z, c0.w, c1.x, c1.y, c1.z, c1.w};
#pragma unroll
            for (int kk = 0; kk < 8; kk++) {
                float v = xc[kk];
#pragma unroll
                for (int q = 0; q < 16; q++) h[q] += v * eW1[(9 + kk) * 16 + q];
            }
#pragma unroll
            for (int q = 0; q < 16; q++) {
                h[q] += ea.x * eW1[17 * 16 + q];
                h[q] += ea.y * eW1[18 * 16 + q];
            }
            float s0 = eB2[0], s1 = eB2[1];
#pragma unroll
            for (int q = 0; q < 16; q++) {
                float rr = fmaxf(h[q], 0.f);
                s0 += rr * eW2[2 * q];
                s1 += rr * eW2[2 * q + 1];
            }
            if (WRITE_EMB) eout[e] = make_float2(s0, s1);
            atomicAdd(&sagg[li][0], s0);
            atomicAdd(&sagg[li][1], s1);
            t0 += s0; t1 += s1;
        }
    }

    if (NEED_SUM) {
        float r0 = wave_red(t0), r1 = wave_red(t1);
        int wave = tid >> 6, lane = tid & 63;
        if (lane == 0) { redE[wave][0] = r0; redE[wave][1] = r1; }
    }
    __syncthreads();   // sagg complete (and redE visible)
    if (NEED_SUM && tid == 0) {
        float s0 = 0.f, s1 = 0.f;
#pragma unroll
        for (int w = 0; w < 8; w++) { s0 += redE[w][0]; s1 += redE[w][1]; }
        atomicAdd(&sums[0], s0);
        atomicAdd(&sums[1], s1);
    }

    // ---------------- phase 2: node MLP (owner threads 0..255) ----------------
    float out[8];
#pragma unroll
    for (int m = 0; m < 8; m++) out[m] = 0.f;

    if (own) {
        int n = n0 + tid;
        float in[11];
        in[0] = gval;
#pragma unroll
        for (int k = 0; k < 8; k++) in[1 + k] = xv[k];
        in[9] = sagg[tid][0]; in[10] = sagg[tid][1];

        float h[16];
#pragma unroll
        for (int q = 0; q < 16; q++) h[q] = nB1[q];
#pragma unroll
        for (int k = 0; k < 11; k++) {
            float v = in[k];
#pragma unroll
            for (int q = 0; q < 16; q++) h[q] += v * nW1[k * 16 + q];
        }
#pragma unroll
        for (int m = 0; m < 8; m++) out[m] = nB2[m];
#pragma unroll
        for (int q = 0; q < 16; q++) {
            float hq = fmaxf(h[q], 0.f);
#pragma unroll
            for (int m = 0; m < 8; m++) out[m] += hq * nW2[q * 8 + m];
        }
        float4* xo = reinterpret_cast<float4*>(xout + (size_t)n * 8);
        xo[0] = make_float4(out[0], out[1], out[2], out[3]);
        xo[1] = make_float4(out[4], out[5], out[6], out[7]);
    }
    if (NEED_SUM) {
        float r[8];
#pragma unroll
        for (int m = 0; m < 8; m++) r[m] = wave_red(out[m]);
        int wave = tid >> 6, lane = tid & 63;
        if (wave < 4 && lane == 0) {
#pragma unroll
            for (int m = 0; m < 8; m++) redN[wave][m] = r[m];
        }
        __syncthreads();
        if (tid == 0) {
#pragma unroll
            for (int m = 0; m < 8; m++) {
                float s = redN[0][m] + redN[1][m] + redN[2][m] + redN[3][m];
                atomicAdd(&sums[2 + m], s);
            }
        }
    }
}

// ---------------- global block: MLP(11->16->1), single thread ----------------
__global__ void glob_kernel(const float* __restrict__ sums,
                            const float* __restrict__ gold,
                            const float* __restrict__ W1, const float* __restrict__ B1,
                            const float* __restrict__ W2, const float* __restrict__ B2,
                            float* __restrict__ gnew)
{
    if (threadIdx.x == 0 && blockIdx.x == 0) {
        float in[11];
#pragma unroll
        for (int j = 0; j < 8; j++) in[j] = sums[2 + j] * (1.0f / NN);
        in[8] = sums[0] * (1.0f / NE);
        in[9] = sums[1] * (1.0f / NE);
        in[10] = gold[0];
        float acc = B2[0];
#pragma unroll
        for (int j = 0; j < 16; j++) {
            float h = B1[j];
#pragma unroll
            for (int k = 0; k < 11; k++) h += in[k] * W1[k * 16 + j];
            acc += fmaxf(h, 0.f) * W2[j];
        }
        gnew[0] = acc;
    }
}

extern "C" void kernel_launch(void* const* d_in, const int* in_sizes, int n_in,
                              void* d_out, int out_size, void* d_ws, size_t ws_size,
                              hipStream_t stream) {
    const float* x     = (const float*)d_in[0];
    const int*   ei    = (const int*)d_in[1];
    const float* eattr = (const float*)d_in[2];
    const float* g     = (const float*)d_in[3];
    const float* eW1 = (const float*)d_in[4];
    const float* eB1 = (const float*)d_in[5];
    const float* eW2 = (const float*)d_in[6];
    const float* eB2 = (const float*)d_in[7];
    const float* nW1 = (const float*)d_in[8];
    const float* nB1 = (const float*)d_in[9];
    const float* nW2 = (const float*)d_in[10];
    const float* nB2 = (const float*)d_in[11];
    const float* gW1 = (const float*)d_in[12];
    const float* gB1 = (const float*)d_in[13];
    const float* gW2 = (const float*)d_in[14];
    const float* gB2 = (const float*)d_in[15];
    float* out = (float*)d_out;

    char* ws = (char*)d_ws;
    float*  xb0   = (float*)(ws);                  // 3,200,000
    float*  xb1   = (float*)(ws + 3200000);        // 3,200,000 -> 6,400,000
    int*    b_off = (int*)  (ws + 6400000);        // 392*4 -> pad 1,600
    float*  sums  = (float*)(ws + 6401600);        // 128 B
    float*  g1    = (float*)(ws + 6401728);
    float*  g2    = g1 + 1;
    int*    keys  = (int*)  (ws + 6401792);        // NE*4 + 8K pad  -> 12,809,984
    float2* attrS = (float2*)(ws + 12809984);      // NE*8 + 16K pad -> 25,626,368
    float2* eembS = (float2*)(ws + 25626368);      // NE*8 + 16K pad -> 38,442,752
    // build-phase temporaries alias xb1 (dead until layer-1 phase 2):
    int*    hist     = (int*)xb1;                          // 391*391*4 = 611,524
    int*    baseT    = (int*)((char*)xb1 + 611584);        // 611,524
    int*    colTotal = (int*)((char*)xb1 + 1223168);       // 1,564

    dim3 blk(256);
    dim3 fblk(512);
    dim3 cgrid(NCHUNK);                            // 391 chunks
    dim3 bgrid(NBUCK);                             // 391 buckets

    // ---- bucket-sort build (no global atomics) ----
    hipMemsetAsync(sums, 0, 128, stream);
    hist_kernel<<<cgrid, blk, 0, stream>>>(ei, hist);
    bscan_kernel<<<bgrid, 512, 0, stream>>>(hist, baseT, colTotal);
    boff_kernel<<<1, 512, 0, stream>>>(colTotal, b_off);
    fillb_kernel<<<cgrid, blk, 0, stream>>>(ei, eattr, baseT, b_off, keys, attrS);

    // ---- layer 0: x(d_in) -> xb0; attrS -> eembS ----
    fused_kernel<true, true><<<bgrid, fblk, 0, stream>>>(
        keys, attrS, eembS, b_off, g,
        eW1, eB1, eW2, eB2,
        x, nW1, nB1, nW2, nB2,
        xb0, sums);
    glob_kernel<<<1, 64, 0, stream>>>(sums, g, gW1, gB1, gW2, gB2, g1);

    // ---- layer 1: xb0 -> xb1; eembS -> eembS (same-slot rewrite, chunk-safe) ----
    fused_kernel<true, true><<<bgrid, fblk, 0, stream>>>(
        keys, eembS, eembS, b_off, g1,
        eW1 + 304, eB1 + 16, eW2 + 32, eB2 + 2,
        xb0, nW1 + 176, nB1 + 16, nW2 + 128, nB2 + 8,
        xb1, sums + 16);
    glob_kernel<<<1, 64, 0, stream>>>(sums + 16, g1, gW1 + 176, gB1 + 16, gW2 + 16, gB2 + 1, g2);

    // ---- layer 2: xb1 -> d_out; no emb write, no sums ----
    fused_kernel<false, false><<<bgrid, fblk, 0, stream>>>(
        keys, eembS, nullptr, b_off, g2,
        eW1 + 608, eB1 + 32, eW2 + 64, eB2 + 4,
        xb1, nW1 + 352, nB1 + 32, nW2 + 256, nB2 + 16,
        out, sums);
}